// Round 4
// baseline (128.762 us; speedup 1.0000x reference)
//
#include <hip/hip_runtime.h>
#include <hip/hip_bf16.h>

typedef __bf16 bf16x8 __attribute__((ext_vector_type(8)));
typedef float floatx4 __attribute__((ext_vector_type(4)));

constexpr int SEQ = 4096;
constexpr int NH  = 8;
constexpr int DH  = 128;
constexpr int BLK = 64;
constexpr int QBLOCKS = SEQ / BLK;   // 64
constexpr int RS = NH * DH;          // 1024 floats per token row
constexpr float SCALE = 0.088388347648318447f;  // 1/sqrt(128)

// LDS plan (two phases, union'd):
//  phase A (k-loop):  v_lds  2 groups x 16384 B      @ 0
//                     p_lds  8 waves  x 2304 B       @ 32768   (total 51200)
//  phase B (combine): comb_O 64x132 fp32 (33792 B)   @ 0
//                     comb_m 64 fp32                 @ 33792
//                     comb_l 64 fp32                 @ 34048
constexpr int SMEM_BYTES = 51200;

// fp32 global -> bf16x8 fragment
__device__ __forceinline__ bf16x8 load8f(const float* p) {
    float4 a = *(const float4*)p;
    float4 b = *(const float4*)(p + 4);
    bf16x8 r = { (__bf16)a.x, (__bf16)a.y, (__bf16)a.z, (__bf16)a.w,
                 (__bf16)b.x, (__bf16)b.y, (__bf16)b.z, (__bf16)b.w };
    return r;
}

// Cooperative V-tile staging (per 4-wave group, 256 threads) into
// fragment-major LDS: frag for mfma (s2,n) at lane L = 16 contiguous bytes
// -> one ds_read_b128. Thread: col n_t = tg&127, k-half kh = tg>>7.
__device__ __forceinline__ void stage_v(const float* __restrict__ V,
                                        int kb, int h, int n_t, int kh,
                                        __bf16* __restrict__ dst) {
    const float* base = V + (size_t)(kb * BLK + kh * 32) * RS + h * DH + n_t;
    const int nt = n_t >> 4;
    const int lbase = n_t & 15;
#pragma unroll
    for (int g = 0; g < 4; ++g) {
        bf16x8 pk;
#pragma unroll
        for (int j = 0; j < 8; ++j)
            pk[j] = (__bf16)base[(size_t)(g * 8 + j) * RS];
        __bf16* d = dst + ((size_t)((kh * 8 + nt) * 64 + lbase + 16 * g)) * 8;
        *(bf16x8*)d = pk;
    }
}

// Block-sparse flash attention, PATTERN_ID=0.
// Visible k-blocks for q-block i: {0,1,i-1,i} ∩ [0,i]; block-granular mask.
// 8 waves: group g = wave>>2 handles k-slots {2g, 2g+1}; groups merge via
// flash-style rescale at the end (halves the serial k-chain, doubles waves).
__global__ __launch_bounds__(512, 4) void sparse_attn_kernel(
    const float* __restrict__ Q,
    const float* __restrict__ K,
    const float* __restrict__ V,
    float* __restrict__ Out)
{
    const int qb   = blockIdx.x;
    const int h    = blockIdx.y;
    const int tid  = threadIdx.x;
    const int wave = tid >> 6;          // 0..7
    const int g    = wave >> 2;         // k-group 0/1
    const int ws   = wave & 3;          // q-strip within group
    const int lane = tid & 63;
    const int quad = lane >> 4;
    const int l16  = lane & 15;

    __shared__ __align__(16) char smem[SMEM_BYTES];
    __bf16* v_g    = (__bf16*)(smem + g * 16384);
    __bf16* p_w    = (__bf16*)(smem + 32768 + wave * 2304);  // [16][72] bf16
    float*  comb_O = (float*)smem;                            // [64][132]
    float*  comb_m = (float*)(smem + 33792);
    float*  comb_l = (float*)(smem + 34048);

    const int tg  = tid & 255;   // thread index within group
    const int n_t = tg & 127;
    const int kh  = tg >> 7;

    // ---- Q strip A-fragments: rows m = l16, k-chunks of 32 (quad*8+j) ----
    const int qrow = qb * BLK + ws * 16 + l16;
    const float* qp = Q + (size_t)qrow * RS + h * DH;
    bf16x8 qfrag[4];
#pragma unroll
    for (int s = 0; s < 4; ++s)
        qfrag[s] = load8f(qp + s * 32 + quad * 8);

    // ---- accumulators ----
    floatx4 o_acc[8];
#pragma unroll
    for (int n = 0; n < 8; ++n) o_acc[n] = floatx4{0.f, 0.f, 0.f, 0.f};
    float m_run[4], l_run[4];
#pragma unroll
    for (int r = 0; r < 4; ++r) { m_run[r] = -1e30f; l_run[r] = 0.f; }

    // ---- visible k-block list (unique, ascending) ----
    int blist[4];
    int nb = 0;
    {
        int cand[4] = {0, 1, qb - 1, qb};
        for (int i = 0; i < 4; ++i) {
            int b = cand[i];
            if (b < 0 || b > qb) continue;
            bool dup = false;
            for (int j = 0; j < nb; ++j) dup = dup || (blist[j] == b);
            if (!dup) blist[nb++] = b;
        }
    }

    // ---- k-loop: fixed 2 trips per group (uniform barriers) ----
#pragma unroll 1
    for (int t = 0; t < 2; ++t) {
        const int s    = 2 * g + t;
        const bool valid = (s < nb);
        const int kb   = valid ? blist[s] : 0;

        if (valid) stage_v(V, kb, h, n_t, kh, v_g);
        __syncthreads();   // v_g staged (and prev iter's readers done)

        if (valid) {
            // ---- S = Q K^T (16x64, 4 n-tiles); K frags direct from global
            floatx4 sfrag[4];
#pragma unroll
            for (int n = 0; n < 4; ++n) {
                floatx4 c = floatx4{0.f, 0.f, 0.f, 0.f};
                const float* kp =
                    K + (size_t)(kb * BLK + n * 16 + l16) * RS + h * DH;
#pragma unroll
                for (int sx = 0; sx < 4; ++sx) {
                    bf16x8 kf = load8f(kp + sx * 32 + quad * 8);
                    c = __builtin_amdgcn_mfma_f32_16x16x32_bf16(qfrag[sx], kf, c, 0, 0, 0);
                }
                sfrag[n] = c;
            }

            // ---- online softmax (row = quad*4+r, stats replicated over l16)
            float mnew[4];
#pragma unroll
            for (int r = 0; r < 4; ++r) {
                float mx = m_run[r];
#pragma unroll
                for (int n = 0; n < 4; ++n) {
                    sfrag[n][r] *= SCALE;
                    mx = fmaxf(mx, sfrag[n][r]);
                }
#pragma unroll
                for (int off = 1; off < 16; off <<= 1)
                    mx = fmaxf(mx, __shfl_xor(mx, off, 64));
                mnew[r] = mx;
            }
#pragma unroll
            for (int r = 0; r < 4; ++r) {
                float alpha = __expf(m_run[r] - mnew[r]);
                float rs = 0.f;
#pragma unroll
                for (int n = 0; n < 4; ++n) {
                    float p = __expf(sfrag[n][r] - mnew[r]);
                    sfrag[n][r] = p;
                    rs += p;
                }
#pragma unroll
                for (int off = 1; off < 16; off <<= 1)
                    rs += __shfl_xor(rs, off, 64);
                l_run[r] = l_run[r] * alpha + rs;
                m_run[r] = mnew[r];
#pragma unroll
                for (int n = 0; n < 8; ++n) o_acc[n][r] *= alpha;
            }

            // ---- P: C-layout -> per-wave LDS -> A-layout (no barrier)
#pragma unroll
            for (int n = 0; n < 4; ++n)
#pragma unroll
                for (int r = 0; r < 4; ++r)
                    p_w[(quad * 4 + r) * 72 + n * 16 + l16] = (__bf16)sfrag[n][r];

            // ---- O += P V : single b128 LDS read per B-frag
#pragma unroll
            for (int s2 = 0; s2 < 2; ++s2) {
                bf16x8 pa = *(const bf16x8*)&p_w[l16 * 72 + s2 * 32 + quad * 8];
#pragma unroll
                for (int n = 0; n < 8; ++n) {
                    bf16x8 vb = *(const bf16x8*)&v_g[((s2 * 8 + n) * 64 + lane) * 8];
                    o_acc[n] = __builtin_amdgcn_mfma_f32_16x16x32_bf16(pa, vb, o_acc[n], 0, 0, 0);
                }
            }
        }
        __syncthreads();   // v_g/p_lds free for reuse (next stage / combine)
    }

    // ---- cross-group flash merge: g1 -> LDS, g0 merges + stores ----
    if (g == 1) {
#pragma unroll
        for (int r = 0; r < 4; ++r) {
            const int row = ws * 16 + quad * 4 + r;
#pragma unroll
            for (int n = 0; n < 8; ++n)
                comb_O[row * 132 + n * 16 + l16] = o_acc[n][r];
            comb_m[row] = m_run[r];   // 16 lanes write same value: benign
            comb_l[row] = l_run[r];
        }
    }
    __syncthreads();
    if (g == 0) {
#pragma unroll
        for (int r = 0; r < 4; ++r) {
            const int row = ws * 16 + quad * 4 + r;
            const float m1 = comb_m[row];
            const float l1 = comb_l[row];
            const float ms = fmaxf(m_run[r], m1);
            const float f0 = __expf(m_run[r] - ms);
            const float f1 = __expf(m1 - ms);
            const float linv = 1.f / (f0 * l_run[r] + f1 * l1);
            float* op = Out + (size_t)(qb * BLK + row) * RS + h * DH + l16;
#pragma unroll
            for (int n = 0; n < 8; ++n)
                op[n * 16] = (f0 * o_acc[n][r] +
                              f1 * comb_O[row * 132 + n * 16 + l16]) * linv;
        }
    }
}

extern "C" void kernel_launch(void* const* d_in, const int* in_sizes, int n_in,
                              void* d_out, int out_size, void* d_ws, size_t ws_size,
                              hipStream_t stream) {
    const float* Q = (const float*)d_in[0];
    const float* K = (const float*)d_in[1];
    const float* V = (const float*)d_in[2];
    // d_in[3] (block_mask) is deterministic from PATTERN_ID=0; hardcoded.
    float* Out = (float*)d_out;

    dim3 grid(QBLOCKS, NH);
    dim3 block(512);
    sparse_attn_kernel<<<grid, block, 0, stream>>>(Q, K, V, Out);
}